// Round 1
// baseline (234.522 us; speedup 1.0000x reference)
//
#include <hip/hip_runtime.h>
#include <hip/hip_bf16.h>

// Linear attention (ELU+1 feature map), N=8, L=S=8192, H=8, D=32, fp32.
// out[n,l,h,v] = (q . KV[n,h,:,v]) / (q . Ksum[n,h,:] + eps),  q = elu(Q)+1
// KV = sum_s elu1(K_s) outer V_s ; Ksum = sum_s elu1(K_s)
// (the /S and *S of the reference cancel exactly)

#define NN 8
#define LL 8192
#define SS 8192
#define HH 8
#define DD 32
#define HD (HH*DD)                 // 256
#define EPSF 1e-6f

#define KV_FLOATS (NN*HH*DD*DD)    // 65536
#define KS_FLOATS (NN*HH*DD)       // 2048
#define FINAL_FLOATS (KV_FLOATS + KS_FLOATS) // 67584

// ---- phase 1 config ----
#define P1_CHUNKS 64               // s-chunks per n
#define P1_BLOCKS (NN*P1_CHUNKS)   // 512 blocks of 512 threads
#define P1_CS (SS/P1_CHUNKS)       // 128 s per block
#define P1_TS 8                    // s staged per iteration
#define PBLK 8448                  // floats per partial block (8192 KV + 256 ksum)

// ---- phase 2 config ----
#define P2_TS 8                    // l staged per iteration
#define P2_LB 64                   // l per block
#define P2_CHUNKS (LL/P2_LB)       // 128 -> grid 1024

__device__ __forceinline__ float elu1(float x) {
    // elu(x)+1 : x>0 -> x+1 ; x<=0 -> exp(x)
    return x > 0.f ? x + 1.f : __expf(x);
}

// ============================ phase 1 =====================================
// block: 512 threads. thread t: vh = t>>8 (v half), h=(t>>5)&7, d=t&31.
// Accumulates KV[h][d][vh*16 .. +15] and Ksum[h][d] over its s-chunk.
template<bool ATOMIC>
__global__ __launch_bounds__(512)
void la_phase1(const float* __restrict__ keys, const float* __restrict__ values,
               float* __restrict__ outbuf) {
    __shared__ float lK[P1_TS*HD];   // 8 KB
    __shared__ float lV[P1_TS*HD];   // 8 KB
    const int t = threadIdx.x;
    const int b = blockIdx.x;
    const int n = b / P1_CHUNKS;
    const int s0 = (b % P1_CHUNKS) * P1_CS;
    const int vh = t >> 8;
    const int h = (t >> 5) & 7;
    const int d = t & 31;

    const float4* Kg = (const float4*)(keys + ((size_t)n*SS + s0) * HD);
    const float4* Vg = (const float4*)(values + ((size_t)n*SS + s0) * HD);
    float4* lK4 = (float4*)lK;
    float4* lV4 = (float4*)lV;

    float acc[16];
#pragma unroll
    for (int i = 0; i < 16; ++i) acc[i] = 0.f;
    float ks = 0.f;

    // prefetch first chunk (512 float4 per tensor, 1 per thread)
    float4 kreg = Kg[t];
    float4 vreg = Vg[t];

    for (int si = 0; si < P1_CS; si += P1_TS) {
        kreg.x = elu1(kreg.x); kreg.y = elu1(kreg.y);
        kreg.z = elu1(kreg.z); kreg.w = elu1(kreg.w);
        __syncthreads();            // previous compute finished reading LDS
        lK4[t] = kreg;
        lV4[t] = vreg;
        __syncthreads();
        if (si + P1_TS < P1_CS) {   // prefetch next chunk; overlaps compute below
            kreg = Kg[(si + P1_TS)*(HD/4) + t];
            vreg = Vg[(si + P1_TS)*(HD/4) + t];
        }
        const float* lVb = lV + h*DD + vh*16;
#pragma unroll
        for (int i = 0; i < P1_TS; ++i) {
            const float kv = lK[i*HD + h*DD + d];   // stride-1 per half-wave
            ks += kv;
            const float4* vp = (const float4*)(lVb + i*HD);  // broadcast reads
#pragma unroll
            for (int j4 = 0; j4 < 4; ++j4) {
                const float4 vv = vp[j4];
                acc[j4*4+0] = fmaf(kv, vv.x, acc[j4*4+0]);
                acc[j4*4+1] = fmaf(kv, vv.y, acc[j4*4+1]);
                acc[j4*4+2] = fmaf(kv, vv.z, acc[j4*4+2]);
                acc[j4*4+3] = fmaf(kv, vv.w, acc[j4*4+3]);
            }
        }
    }

    if (ATOMIC) {
        float* kvdst = outbuf + ((size_t)(n*HH + h)*DD + d)*DD + vh*16;
#pragma unroll
        for (int j = 0; j < 16; ++j) atomicAdd(kvdst + j, acc[j]);
        if (vh == 0) atomicAdd(outbuf + KV_FLOATS + (n*HH + h)*DD + d, ks);
    } else {
        float* pb = outbuf + (size_t)b * PBLK;
        float4* kvdst = (float4*)(pb + (h*DD + d)*DD + vh*16);
#pragma unroll
        for (int j4 = 0; j4 < 4; ++j4)
            kvdst[j4] = make_float4(acc[j4*4+0], acc[j4*4+1], acc[j4*4+2], acc[j4*4+3]);
        if (vh == 0) pb[8192 + h*DD + d] = ks;
    }
}

// ============================ reduce ======================================
// Sums P1_CHUNKS partials per n. 264 blocks x 256 = 67584 output floats.
__global__ __launch_bounds__(256)
void la_reduce(const float* __restrict__ part, float* __restrict__ finalbuf) {
    const int o = blockIdx.x * 256 + threadIdx.x;   // 0 .. FINAL_FLOATS-1
    const int n = o / PBLK;
    const int e = o - n * PBLK;
    const float* p = part + (size_t)(n * P1_CHUNKS) * PBLK + e;
    float s = 0.f;
#pragma unroll 8
    for (int c = 0; c < P1_CHUNKS; ++c) s += p[(size_t)c * PBLK];
    if (e < HH*DD*DD) finalbuf[(size_t)n*(HH*DD*DD) + e] = s;
    else              finalbuf[KV_FLOATS + n*HD + (e - HH*DD*DD)] = s;
}

// ============================ phase 2 =====================================
// block: 256 threads, 64 l per block. LDS = 32KB KV + 8KB Q = 40KB -> 4 blk/CU.
// compute mapping: i2=t>>6 (handles i=i2, i2+4), hC=(t>>6? no) see below.
__global__ __launch_bounds__(256)
void la_phase2(const float* __restrict__ queries, const float* __restrict__ finalbuf,
               float* __restrict__ out) {
    __shared__ float lKV[HH*DD*DD];  // 32 KB  [h][d][v]
    __shared__ float lQ[P2_TS*HD];   // 8 KB   [i][h][d]
    const int t = threadIdx.x;
    const int b = blockIdx.x;
    const int n = b / P2_CHUNKS;
    const int l0 = (b % P2_CHUNKS) * P2_LB;

    // stage KV for this n
    const float4* kvg = (const float4*)(finalbuf + (size_t)n * (HH*DD*DD));
    float4* lKV4 = (float4*)lKV;
#pragma unroll
    for (int i = 0; i < 8; ++i) lKV4[t + i*256] = kvg[t + i*256];

    const int hA  = (t >> 3) & 7;   // staging h
    const int d4A = t & 7;          // staging d4
    const int i2  = t >> 6;         // compute i-group (0..3)
    const int r   = t & 63;
    const int hC  = r >> 3;         // compute h
    const int v4C = r & 7;          // compute v4

    // Ksum fragment for this thread's staged (h,d4): direct from global (L2 hit)
    const float4 ksA = ((const float4*)(finalbuf + KV_FLOATS + (size_t)n*HD))[hA*8 + d4A];

    const float4* Qg = (const float4*)(queries + ((size_t)n*LL + l0) * HD);
    float4 q[2];
    q[0] = Qg[t];
    q[1] = Qg[t + 256];

    __syncthreads();   // lKV visible

    for (int li = 0; li < P2_LB; li += P2_TS) {
        // ELU + per-(l,h) normalizer dot, reduced over the 8 d4-lanes
        float zp[2];
#pragma unroll
        for (int c = 0; c < 2; ++c) {
            q[c].x = elu1(q[c].x); q[c].y = elu1(q[c].y);
            q[c].z = elu1(q[c].z); q[c].w = elu1(q[c].w);
            float zz = q[c].x*ksA.x + q[c].y*ksA.y + q[c].z*ksA.z + q[c].w*ksA.w;
            zz += __shfl_xor(zz, 1);
            zz += __shfl_xor(zz, 2);
            zz += __shfl_xor(zz, 4);
            zp[c] = zz;   // replicated across the 8-lane group; lane hA*8 holds (i2(+4),hA)
        }
        __syncthreads();            // previous compute finished reading lQ
        ((float4*)lQ)[t]       = q[0];
        ((float4*)lQ)[t + 256] = q[1];
        __syncthreads();
        if (li + P2_TS < P2_LB) {   // prefetch next l-chunk
            q[0] = Qg[(li + P2_TS)*(HD/4) + t];
            q[1] = Qg[(li + P2_TS)*(HD/4) + t + 256];
        }

        // y[k] = out row for i = i2 + 4k  (k=0,1), columns v4C*4..+3
        float4 y[2];
        y[0] = make_float4(0.f,0.f,0.f,0.f);
        y[1] = make_float4(0.f,0.f,0.f,0.f);
        const float* kvb = lKV + hC*(DD*DD);
#pragma unroll
        for (int d4 = 0; d4 < 8; ++d4) {
            float4 qv0 = *(const float4*)(lQ + (i2    )*HD + hC*DD + d4*4);
            float4 qv1 = *(const float4*)(lQ + (i2 + 4)*HD + hC*DD + d4*4);
#pragma unroll
            for (int j = 0; j < 4; ++j) {
                const float4 kvv = *(const float4*)(kvb + (d4*4 + j)*DD + v4C*4);
                const float q0 = (&qv0.x)[j];
                const float q1 = (&qv1.x)[j];
                y[0].x = fmaf(q0, kvv.x, y[0].x);
                y[0].y = fmaf(q0, kvv.y, y[0].y);
                y[0].z = fmaf(q0, kvv.z, y[0].z);
                y[0].w = fmaf(q0, kvv.w, y[0].w);
                y[1].x = fmaf(q1, kvv.x, y[1].x);
                y[1].y = fmaf(q1, kvv.y, y[1].y);
                y[1].z = fmaf(q1, kvv.z, y[1].z);
                y[1].w = fmaf(q1, kvv.w, y[1].w);
            }
        }
        // Z via in-wave shuffle from the staging lane of (i, hC)
#pragma unroll
        for (int k = 0; k < 2; ++k) {
            const float zs = __shfl(zp[k], hC * 8);     // lane (hC*8) of this wave
            const float z = 1.0f / (zs + EPSF);
            float4 yy = y[k];
            yy.x *= z; yy.y *= z; yy.z *= z; yy.w *= z;
            const int l = l0 + li + i2 + 4*k;
            float4* dst = (float4*)(out + ((size_t)n*LL + l)*HD + hC*DD);
            dst[v4C] = yy;
        }
    }
}

// ============================ launch ======================================
extern "C" void kernel_launch(void* const* d_in, const int* in_sizes, int n_in,
                              void* d_out, int out_size, void* d_ws, size_t ws_size,
                              hipStream_t stream) {
    const float* q = (const float*)d_in[0];
    const float* k = (const float*)d_in[1];
    const float* v = (const float*)d_in[2];
    float* out = (float*)d_out;

    const size_t partial_floats = (size_t)P1_BLOCKS * PBLK;
    const size_t need = (partial_floats + FINAL_FLOATS) * sizeof(float);

    if (ws_size >= need) {
        float* part = (float*)d_ws;
        float* fin  = part + partial_floats;
        la_phase1<false><<<dim3(P1_BLOCKS), dim3(512), 0, stream>>>(k, v, part);
        la_reduce<<<dim3(FINAL_FLOATS/256), dim3(256), 0, stream>>>(part, fin);
        la_phase2<<<dim3(NN*P2_CHUNKS), dim3(256), 0, stream>>>(q, fin, out);
    } else {
        // fallback: tiny ws -> atomic accumulation into final buffer
        float* fin = (float*)d_ws;
        hipMemsetAsync(fin, 0, FINAL_FLOATS*sizeof(float), stream);
        la_phase1<true><<<dim3(P1_BLOCKS), dim3(512), 0, stream>>>(k, v, fin);
        la_phase2<<<dim3(NN*P2_CHUNKS), dim3(256), 0, stream>>>(q, fin, out);
    }
}